// Round 6
// baseline (302.562 us; speedup 1.0000x reference)
//
#include <hip/hip_runtime.h>
#include <hip/hip_bf16.h>

#define NFEAT 9
#define VOCAB 119
#define HIDDEN 128
#define NHEAD 8
#define HDIM 16
#define KNBR 16

// ---------- sentinel fill (distinguishable failure signatures) ----------
__global__ void fill_kernel(float* out, int n, float val) {
    int i = blockIdx.x * blockDim.x + threadIdx.x;
    if (i < n) out[i] = val;
}

// ---------- stage 1: h[n][c] = sum_f emb[f, X[n,f], c] ----------
// ints confirmed int32 (r5 width-detector output bit-identical to r4 hardcoded int32)
__global__ void h_kernel(const int* __restrict__ X, const float* __restrict__ emb,
                         float* __restrict__ h, int N) {
    int n = blockIdx.x;
    int c = threadIdx.x;
    __shared__ int xs[NFEAT];
    if (c < NFEAT) {
        int v = X[(size_t)n * NFEAT + c];
        xs[c] = min(max(v, 0), VOCAB - 1);   // clamp: never fault
    }
    __syncthreads();
    float acc = 0.f;
    for (int f = 0; f < NFEAT; ++f)
        acc += emb[((size_t)f * VOCAB + xs[f]) * HIDDEN + c];
    h[(size_t)n * HIDDEN + c] = acc;
}

// ---------- stage 2: q/k/v projections, 4 nodes per block ----------
// Loop-blocked over nodes: W element loaded once per 4 nodes (2.4 GB L2 traffic
// instead of 9.6 GB at 1 node/block). 12 accumulators + 3 weights in registers.
#define PNB 4
__global__ __launch_bounds__(128) void proj_kernel(
    const float* __restrict__ h,
    const float* __restrict__ Wq, const float* __restrict__ bq,
    const float* __restrict__ Wk, const float* __restrict__ bk,
    const float* __restrict__ Wv, const float* __restrict__ bv,
    float* __restrict__ q, float* __restrict__ k, float* __restrict__ v, int N) {
    int n0 = blockIdx.x * PNB;
    int c = threadIdx.x;
    __shared__ float hr[PNB][HIDDEN];
    #pragma unroll
    for (int j = 0; j < PNB; ++j)
        hr[j][c] = (n0 + j < N) ? h[(size_t)(n0 + j) * HIDDEN + c] : 0.f;
    __syncthreads();
    float aq[PNB], ak[PNB], av[PNB];
    float vbq = bq[c], vbk = bk[c], vbv = bv[c];
    #pragma unroll
    for (int j = 0; j < PNB; ++j) { aq[j] = vbq; ak[j] = vbk; av[j] = vbv; }
    for (int cc = 0; cc < HIDDEN; ++cc) {
        float wq = Wq[cc * HIDDEN + c];   // (h @ W)[n,c] = sum_cc h[n,cc] * W[cc,c]
        float wk = Wk[cc * HIDDEN + c];
        float wv = Wv[cc * HIDDEN + c];
        #pragma unroll
        for (int j = 0; j < PNB; ++j) {
            float hv = hr[j][cc];
            aq[j] += hv * wq; ak[j] += hv * wk; av[j] += hv * wv;
        }
    }
    #pragma unroll
    for (int j = 0; j < PNB; ++j) {
        if (n0 + j < N) {
            q[(size_t)(n0 + j) * HIDDEN + c] = aq[j] * 0.25f;  // HEAD_DIM^-0.5 folded
            k[(size_t)(n0 + j) * HIDDEN + c] = ak[j];
            v[(size_t)(n0 + j) * HIDDEN + c] = av[j];
        }
    }
}

// ---------- stage 3: ELL attention, one node per 128-thread block ----------
__global__ void attn_kernel(const int* __restrict__ nbr_idx,
                            const int* __restrict__ nbr_mask,
                            const float* __restrict__ q, const float* __restrict__ k,
                            const float* __restrict__ v,
                            float* __restrict__ out, int N) {
    int n = blockIdx.x;
    int t = threadIdx.x;
    __shared__ float ql[HIDDEN];
    __shared__ int idx[KNBR];
    __shared__ int msk[KNBR];
    __shared__ float sl[KNBR][NHEAD];
    __shared__ float el[KNBR][NHEAD];
    __shared__ float al[KNBR][NHEAD];

    ql[t] = q[(size_t)n * HIDDEN + t];
    if (t < KNBR) {
        int iv = nbr_idx[(size_t)n * KNBR + t];
        idx[t] = min(max(iv, 0), N - 1);     // clamp: never fault
        msk[t] = nbr_mask[(size_t)n * KNBR + t];
    }
    __syncthreads();

    // scores: thread -> (neighbor kk, head hh)
    int kk = t >> 3, hh = t & 7;
    float s = 0.f;
    {
        const float* kr = k + (size_t)idx[kk] * HIDDEN + hh * HDIM;
        for (int d = 0; d < HDIM; ++d) s += ql[hh * HDIM + d] * kr[d];
    }
    if (!msk[kk]) s = -1e9f;
    sl[kk][hh] = s;
    __syncthreads();

    float mx = -3e38f;
    for (int j = 0; j < KNBR; ++j) mx = fmaxf(mx, sl[j][hh]);
    float e = __expf(s - mx);          // all-masked row -> uniform 1/16, matches softmax
    el[kk][hh] = e;
    __syncthreads();
    float den = 0.f;
    for (int j = 0; j < KNBR; ++j) den += el[j][hh];
    al[kk][hh] = e / den;
    __syncthreads();

    // PV: thread -> (head h2, dim dd); out channel = h2*16+dd = t
    int h2 = t >> 4, dd = t & 15;
    float o = 0.f;
    for (int j = 0; j < KNBR; ++j)
        o += al[j][h2] * v[(size_t)idx[j] * HIDDEN + h2 * HDIM + dd];
    // OUTPUT IS FLOAT32: reference returns fp32; harness doc maps fp32 -> float*.
    // (r2-r5's 0.224 plateau == bf16-pairs-misread-as-fp32 signature.)
    out[(size_t)n * HIDDEN + t] = o;
}

extern "C" void kernel_launch(void* const* d_in, const int* in_sizes, int n_in,
                              void* d_out, int out_size, void* d_ws, size_t ws_size,
                              hipStream_t stream)
{
    float* out = (float*)d_out;

    // ---- host-side contract validation (deterministic -> graph-capture safe) ----
    bool ok = (n_in == 10);
    int N = ok ? in_sizes[0] / NFEAT : 0;
    ok = ok && N > 0 && in_sizes[0] == N * NFEAT
            && in_sizes[1] == N * KNBR
            && in_sizes[2] == N * KNBR
            && in_sizes[3] == NFEAT * VOCAB * HIDDEN
            && in_sizes[4] == HIDDEN * HIDDEN && in_sizes[5] == HIDDEN
            && in_sizes[6] == HIDDEN * HIDDEN && in_sizes[7] == HIDDEN
            && in_sizes[8] == HIDDEN * HIDDEN && in_sizes[9] == HIDDEN
            && out_size == N * HIDDEN;
    if (!ok) {  // SENTINEL A: shape/order mismatch -> zeros -> absmax 1.982e-1
        fill_kernel<<<(out_size + 255) / 256, 256, 0, stream>>>(out, out_size, 0.0f);
        return;
    }
    size_t need = (size_t)N * HIDDEN * sizeof(float) * 4;  // h,q,k,v fp32
    if (ws_size < need) {  // SENTINEL B: workspace too small -> ones
        fill_kernel<<<(out_size + 255) / 256, 256, 0, stream>>>(out, out_size, 1.0f);
        return;
    }

    const int* X        = (const int*)d_in[0];
    const int* nbr_idx  = (const int*)d_in[1];
    const int* nbr_mask = (const int*)d_in[2];
    const float* emb = (const float*)d_in[3];
    const float* Wq  = (const float*)d_in[4];
    const float* bq  = (const float*)d_in[5];
    const float* Wk  = (const float*)d_in[6];
    const float* bk  = (const float*)d_in[7];
    const float* Wv  = (const float*)d_in[8];
    const float* bv  = (const float*)d_in[9];

    float* h = (float*)d_ws;
    float* q = h + (size_t)N * HIDDEN;
    float* k = q + (size_t)N * HIDDEN;
    float* v = k + (size_t)N * HIDDEN;

    h_kernel<<<N, HIDDEN, 0, stream>>>(X, emb, h, N);
    proj_kernel<<<(N + PNB - 1) / PNB, HIDDEN, 0, stream>>>(
        h, Wq, bq, Wk, bk, Wv, bv, q, k, v, N);
    attn_kernel<<<N, HIDDEN, 0, stream>>>(nbr_idx, nbr_mask, q, k, v, out, N);
}

// Round 7
// 241.988 us; speedup vs baseline: 1.2503x; 1.2503x over previous
//
#include <hip/hip_runtime.h>
#include <hip/hip_bf16.h>

#define NFEAT 9
#define VOCAB 119
#define HIDDEN 128
#define NHEAD 8
#define HDIM 16
#define KNBR 16

// ---------- sentinel fill (distinguishable failure signatures) ----------
__global__ void fill_kernel(float* out, int n, float val) {
    int i = blockIdx.x * blockDim.x + threadIdx.x;
    if (i < n) out[i] = val;
}

// ---------------- Kernel 1: fused atom-encoder + QKV projection ----------------
// 16 nodes/block, 256 threads. h staged transposed in LDS (stride 20 floats:
// 16B-aligned float4 rows). Each thread owns 1 output channel x 8 nodes ->
// each W element feeds 8 FMAs; h read as two broadcast float4 (ds_read_b128).
// Outputs: qf fp32 (pre-scaled x0.25), kv bf16 interleaved [N][k(128)|v(128)]
// -> 512 B gather rows for the attention kernel (halves gather traffic).
#define NPB 16
#define HT_STRIDE (NPB + 4) // 20 floats; multiple of 4 keeps float4 alignment

__global__ __launch_bounds__(256) void qkv_kernel(
    const int* __restrict__ X,
    const float* __restrict__ emb,
    const float* __restrict__ Wq, const float* __restrict__ bq,
    const float* __restrict__ Wk, const float* __restrict__ bk,
    const float* __restrict__ Wv, const float* __restrict__ bv,
    float* __restrict__ qf, __hip_bfloat16* __restrict__ kv, int N)
{
    __shared__ float hT[HIDDEN * HT_STRIDE];
    __shared__ int xs[NPB * NFEAT];

    const int tid = threadIdx.x;
    const int n0 = blockIdx.x * NPB;

    if (tid < NPB * NFEAT) {
        int nl = tid / NFEAT, f = tid % NFEAT;
        int n = n0 + nl;
        int v = (n < N) ? X[(size_t)n * NFEAT + f] : 0;
        xs[tid] = min(max(v, 0), VOCAB - 1);  // clamp: never fault
    }
    __syncthreads();

    const int c = tid & 127;     // channel, fixed per thread
    const int half = tid >> 7;   // node-octet selector
    // ---- phase 1: h (fp32 accumulate of embedding gathers), transposed to LDS ----
    #pragma unroll
    for (int i = 0; i < NPB / 2; ++i) {
        int nl = half + 2 * i;
        float acc = 0.f;
        #pragma unroll
        for (int f = 0; f < NFEAT; ++f) {
            int vidx = xs[nl * NFEAT + f];
            acc += emb[((size_t)f * VOCAB + vidx) * HIDDEN + c];
        }
        hT[c * HT_STRIDE + nl] = acc;
    }
    __syncthreads();

    // ---- phase 2: q/k/v GEMV, register-blocked over 8 nodes ----
    const float* hbase = &hT[half * 8];
    #pragma unroll
    for (int m = 0; m < 3; ++m) {
        const float* W = (m == 0) ? Wq : (m == 1) ? Wk : Wv;
        const float* b = (m == 0) ? bq : (m == 1) ? bk : bv;
        float bias = b[c];
        float acc[8];
        #pragma unroll
        for (int j = 0; j < 8; ++j) acc[j] = bias;
        #pragma unroll 4
        for (int cc = 0; cc < HIDDEN; ++cc) {
            float w = W[cc * HIDDEN + c];   // (h@W)[n,c] = sum_cc h[n,cc]*W[cc,c]
            const float4* hp = reinterpret_cast<const float4*>(hbase + cc * HT_STRIDE);
            float4 h0 = hp[0], h1 = hp[1];
            acc[0] += h0.x * w; acc[1] += h0.y * w;
            acc[2] += h0.z * w; acc[3] += h0.w * w;
            acc[4] += h1.x * w; acc[5] += h1.y * w;
            acc[6] += h1.z * w; acc[7] += h1.w * w;
        }
        #pragma unroll
        for (int j = 0; j < 8; ++j) {
            int n = n0 + half * 8 + j;
            if (n < N) {
                if (m == 0)      qf[(size_t)n * HIDDEN + c] = acc[j] * 0.25f; // HEAD_DIM^-0.5
                else if (m == 1) kv[(size_t)n * 256 + c] = __float2bfloat16(acc[j]);
                else             kv[(size_t)n * 256 + 128 + c] = __float2bfloat16(acc[j]);
            }
        }
    }
}

// ---------------- Kernel 2: ELL sparse attention ----------------
// 2 nodes/block (128 threads each). Gather 16 neighbor 512B bf16 kv rows into
// LDS, scores by (nbr,head) threads, LDS softmax (max-subtract handles
// all-masked -> uniform 1/16), PV by (head,dim) threads. Output fp32.
#define NPB2 2
#define KV_LDS_STRIDE 264 // bf16/row = 132 words: +4-bank row offset, 16B aligned

__global__ __launch_bounds__(256) void attn_kernel(
    const int* __restrict__ nbr_idx, const int* __restrict__ nbr_mask,
    const float* __restrict__ qf, const __hip_bfloat16* __restrict__ kv,
    float* __restrict__ out, int N)
{
    __shared__ __hip_bfloat16 kvl[NPB2][KNBR][KV_LDS_STRIDE];
    __shared__ float ql[NPB2][HIDDEN];
    __shared__ float sl[NPB2][KNBR][NHEAD + 1];
    __shared__ float el[NPB2][KNBR][NHEAD + 1];
    __shared__ int idxl[NPB2][KNBR];
    __shared__ int mskl[NPB2][KNBR];

    const int tid = threadIdx.x;
    const int local = tid >> 7; // node within block
    const int t = tid & 127;    // thread within node
    int n = blockIdx.x * NPB2 + local;
    if (n >= N) n = N - 1; // duplicate work instead of early-exit (barrier-safe)

    ql[local][t] = qf[(size_t)n * HIDDEN + t];
    if (t < KNBR) {
        int iv = nbr_idx[(size_t)n * KNBR + t];
        idxl[local][t] = min(max(iv, 0), N - 1);
        mskl[local][t] = nbr_mask[(size_t)n * KNBR + t];
    }
    __syncthreads();

    // gather: each of 128 threads pulls 4B (2 bf16) of the 512B kv row
    #pragma unroll
    for (int kk = 0; kk < KNBR; ++kk) {
        size_t row = (size_t)idxl[local][kk] * 256;
        reinterpret_cast<unsigned int*>(&kvl[local][kk][0])[t] =
            reinterpret_cast<const unsigned int*>(kv + row)[t];
    }
    __syncthreads();

    // scores: thread -> (nbr kk, head hh)
    const int kk = t >> 3, hh = t & 7;
    float s = 0.f;
    {
        const __hip_bfloat162* kp =
            reinterpret_cast<const __hip_bfloat162*>(&kvl[local][kk][hh * HDIM]);
        const float* qp = &ql[local][hh * HDIM];
        #pragma unroll
        for (int d2 = 0; d2 < HDIM / 2; ++d2) {
            float2 kf = __bfloat1622float2(kp[d2]);
            s += qp[2 * d2] * kf.x + qp[2 * d2 + 1] * kf.y;
        }
    }
    if (!mskl[local][kk]) s = -1e9f;
    sl[local][kk][hh] = s;
    __syncthreads();

    float mx = -3.0e38f;
    #pragma unroll
    for (int j = 0; j < KNBR; ++j) mx = fmaxf(mx, sl[local][j][hh]);
    float e = __expf(s - mx);
    el[local][kk][hh] = e;
    __syncthreads();
    float denom = 0.f;
    #pragma unroll
    for (int j = 0; j < KNBR; ++j) denom += el[local][j][hh];
    sl[local][kk][hh] = e / denom; // reuse sl as attn weights
    __syncthreads();

    // PV: thread -> (head h2, dim dd); out channel = h2*16+dd = t
    const int h2 = t >> 4, dd = t & 15;
    float o = 0.f;
    #pragma unroll
    for (int j = 0; j < KNBR; ++j) {
        float a = sl[local][j][h2];
        float vv = __bfloat162float(kvl[local][j][HIDDEN + h2 * HDIM + dd]);
        o += a * vv;
    }
    out[(size_t)n * HIDDEN + t] = o;  // OUTPUT IS FLOAT32 (verified r6)
}

extern "C" void kernel_launch(void* const* d_in, const int* in_sizes, int n_in,
                              void* d_out, int out_size, void* d_ws, size_t ws_size,
                              hipStream_t stream)
{
    float* out = (float*)d_out;

    // ---- host-side contract validation (deterministic -> graph-capture safe) ----
    bool ok = (n_in == 10);
    int N = ok ? in_sizes[0] / NFEAT : 0;
    ok = ok && N > 0 && in_sizes[0] == N * NFEAT
            && in_sizes[1] == N * KNBR
            && in_sizes[2] == N * KNBR
            && in_sizes[3] == NFEAT * VOCAB * HIDDEN
            && in_sizes[4] == HIDDEN * HIDDEN && in_sizes[5] == HIDDEN
            && in_sizes[6] == HIDDEN * HIDDEN && in_sizes[7] == HIDDEN
            && in_sizes[8] == HIDDEN * HIDDEN && in_sizes[9] == HIDDEN
            && out_size == N * HIDDEN;
    if (!ok) {  // SENTINEL A: shape/order mismatch -> zeros
        fill_kernel<<<(out_size + 255) / 256, 256, 0, stream>>>(out, out_size, 0.0f);
        return;
    }
    size_t need = (size_t)N * (HIDDEN * sizeof(float) + 256 * sizeof(__hip_bfloat16));
    if (ws_size < need) {  // SENTINEL B: workspace too small -> ones
        fill_kernel<<<(out_size + 255) / 256, 256, 0, stream>>>(out, out_size, 1.0f);
        return;
    }

    const int* X        = (const int*)d_in[0];
    const int* nbr_idx  = (const int*)d_in[1];
    const int* nbr_mask = (const int*)d_in[2];
    const float* emb = (const float*)d_in[3];
    const float* Wq  = (const float*)d_in[4];
    const float* bq  = (const float*)d_in[5];
    const float* Wk  = (const float*)d_in[6];
    const float* bk  = (const float*)d_in[7];
    const float* Wv  = (const float*)d_in[8];
    const float* bv  = (const float*)d_in[9];

    // workspace: qf fp32 [N][128] | kv bf16 [N][256] (k|v interleaved)
    float* qf = (float*)d_ws;
    __hip_bfloat16* kv =
        (__hip_bfloat16*)((char*)d_ws + (size_t)N * HIDDEN * sizeof(float));

    qkv_kernel<<<(N + NPB - 1) / NPB, 256, 0, stream>>>(
        X, emb, Wq, bq, Wk, bk, Wv, bv, qf, kv, N);
    attn_kernel<<<(N + NPB2 - 1) / NPB2, 256, 0, stream>>>(
        nbr_idx, nbr_mask, qf, kv, out, N);
}

// Round 8
// 197.524 us; speedup vs baseline: 1.5318x; 1.2251x over previous
//
#include <hip/hip_runtime.h>
#include <hip/hip_bf16.h>

#define NFEAT 9
#define VOCAB 119
#define HIDDEN 128
#define NHEAD 8
#define HDIM 16
#define KNBR 16

typedef __attribute__((ext_vector_type(8))) short short8;   // 8 bf16 = 4 VGPRs
typedef __attribute__((ext_vector_type(4))) float f32x4;    // MFMA C/D

// ---------- sentinel fill (distinguishable failure signatures) ----------
__global__ void fill_kernel(float* out, int n, float val) {
    int i = blockIdx.x * blockDim.x + threadIdx.x;
    if (i < n) out[i] = val;
}

// ---------- Kernel 0: W -> W^T bf16 (one-time per launch, 12 blocks) ----------
// Wt[mat][c][cc] = W_mat[cc][c], bf16. B-fragments need k(=cc)-contiguous rows.
__global__ __launch_bounds__(256) void wt_kernel(
    const float* __restrict__ Wq, const float* __restrict__ Wk,
    const float* __restrict__ Wv, short* __restrict__ Wt)
{
    int mat = blockIdx.x >> 2, tile = blockIdx.x & 3;  // 3 mats x 4 row-tiles
    const float* W = (mat == 0) ? Wq : (mat == 1) ? Wk : Wv;
    __shared__ float ls[32 * HIDDEN];
    int tid = threadIdx.x;
    int cc0 = tile * 32;
    #pragma unroll
    for (int j = 0; j < 16; ++j) {
        int idx = j * 256 + tid;
        ls[idx] = W[(size_t)cc0 * HIDDEN + idx];   // coalesced
    }
    __syncthreads();
    int c = tid & 127, hf = tid >> 7;  // thread: output row c, 16 cc's
    unsigned int ob[8];
    #pragma unroll
    for (int j = 0; j < 8; ++j) {
        int ccl = hf * 16 + 2 * j;
        __hip_bfloat16 b0 = __float2bfloat16(ls[ccl * HIDDEN + c]);
        __hip_bfloat16 b1 = __float2bfloat16(ls[(ccl + 1) * HIDDEN + c]);
        ob[j] = (unsigned int)*reinterpret_cast<unsigned short*>(&b0)
              | ((unsigned int)*reinterpret_cast<unsigned short*>(&b1) << 16);
    }
    unsigned int* dst = reinterpret_cast<unsigned int*>(
        Wt + (size_t)mat * HIDDEN * HIDDEN + (size_t)c * HIDDEN + cc0 + hf * 16);
    #pragma unroll
    for (int j = 0; j < 8; ++j) dst[j] = ob[j];
}

// ---------- Kernel 1: fused encoder + MFMA QKV ----------
// 64 nodes/block, 256 threads (4 waves). Encoder writes h as bf16 into LDS in
// A-operand layout (row stride 136 bf16 -> 2-way LDS aliasing = free, m136).
// Per matrix: stage Wt into LDS, each wave computes one 16-node m-tile x 8
// n-tiles via mfma_f32_16x16x32_bf16 (4 k-steps). C mapping (verified m89/m91):
// col=lane&15, row=(lane>>4)*4+reg. fp32 VALU floor was 62us; MFMA floor ~4us.
#define MT 64
#define HBS 136  // padded bf16 row stride; 272B = 4-bank shift/row, 16B aligned

__global__ __launch_bounds__(256) void qkv_kernel(
    const int* __restrict__ X, const float* __restrict__ emb,
    const short* __restrict__ Wt,
    const float* __restrict__ bq, const float* __restrict__ bk,
    const float* __restrict__ bv,
    float* __restrict__ qf, __hip_bfloat16* __restrict__ kv, int N)
{
    __shared__ __align__(16) short hb[MT * HBS];
    __shared__ __align__(16) short Wb[HIDDEN * HBS];
    __shared__ int xs[MT * NFEAT];

    const int tid = threadIdx.x;
    const int n0 = blockIdx.x * MT;

    for (int i = tid; i < MT * NFEAT; i += 256) {
        int n = n0 + i / NFEAT;
        int v = (n < N) ? X[(size_t)n * NFEAT + (i % NFEAT)] : 0;
        xs[i] = min(max(v, 0), VOCAB - 1);  // clamp: never fault
    }
    __syncthreads();

    // ---- encoder: h[nl][c] = sum_f emb[f, X, c], stored bf16 ----
    const int c = tid & 127, half = tid >> 7;
    for (int i = 0; i < MT / 2; ++i) {
        int nl = half * (MT / 2) + i;
        float acc = 0.f;
        #pragma unroll
        for (int f = 0; f < NFEAT; ++f)
            acc += emb[((size_t)f * VOCAB + xs[nl * NFEAT + f]) * HIDDEN + c];
        reinterpret_cast<__hip_bfloat16*>(hb)[nl * HBS + c] = __float2bfloat16(acc);
    }

    const int wave = tid >> 6, lane = tid & 63;
    const int l15 = lane & 15, quad = lane >> 4;
    const int mloc = wave * 16 + l15;  // A-operand row (node within tile)

    for (int mat = 0; mat < 3; ++mat) {
        __syncthreads();  // hb ready (1st iter) / prior LDS reads done before restage
        // stage Wt[mat] -> Wb (coalesced uint4, padded stride)
        const uint4* src = reinterpret_cast<const uint4*>(Wt + (size_t)mat * HIDDEN * HIDDEN);
        #pragma unroll
        for (int j = 0; j < 8; ++j) {
            int idx = j * 256 + tid;       // 2048 uint4 = 16384 bf16
            int r = idx >> 4, o = idx & 15;
            *reinterpret_cast<uint4*>(&Wb[r * HBS + o * 8]) = src[idx];
        }
        __syncthreads();

        short8 a[4];
        #pragma unroll
        for (int k0 = 0; k0 < 4; ++k0)  // A[m=mloc][k=k0*32+quad*8 ..+7]
            a[k0] = *reinterpret_cast<const short8*>(&hb[mloc * HBS + k0 * 32 + quad * 8]);

        const float* bias = (mat == 0) ? bq : (mat == 1) ? bk : bv;
        #pragma unroll
        for (int nt = 0; nt < 8; ++nt) {
            f32x4 acc = {0.f, 0.f, 0.f, 0.f};
            int n = nt * 16 + l15;         // output channel
            #pragma unroll
            for (int k0 = 0; k0 < 4; ++k0) {
                short8 b = *reinterpret_cast<const short8*>(&Wb[n * HBS + k0 * 32 + quad * 8]);
                acc = __builtin_amdgcn_mfma_f32_16x16x32_bf16(a[k0], b, acc, 0, 0, 0);
            }
            float bb = bias[n];
            #pragma unroll
            for (int r = 0; r < 4; ++r) {  // C row = quad*4+r = node within tile
                int node = n0 + wave * 16 + quad * 4 + r;
                if (node < N) {
                    float val = acc[r] + bb;
                    if (mat == 0)      qf[(size_t)node * HIDDEN + n] = val * 0.25f;
                    else if (mat == 1) kv[(size_t)node * 256 + n] = __float2bfloat16(val);
                    else               kv[(size_t)node * 256 + 128 + n] = __float2bfloat16(val);
                }
            }
        }
    }
}

// ---------------- Kernel 2: ELL sparse attention (unchanged from r7) ----------------
#define NPB2 2
#define KV_LDS_STRIDE 264

__global__ __launch_bounds__(256) void attn_kernel(
    const int* __restrict__ nbr_idx, const int* __restrict__ nbr_mask,
    const float* __restrict__ qf, const __hip_bfloat16* __restrict__ kv,
    float* __restrict__ out, int N)
{
    __shared__ __hip_bfloat16 kvl[NPB2][KNBR][KV_LDS_STRIDE];
    __shared__ float ql[NPB2][HIDDEN];
    __shared__ float sl[NPB2][KNBR][NHEAD + 1];
    __shared__ float el[NPB2][KNBR][NHEAD + 1];
    __shared__ int idxl[NPB2][KNBR];
    __shared__ int mskl[NPB2][KNBR];

    const int tid = threadIdx.x;
    const int local = tid >> 7;
    const int t = tid & 127;
    int n = blockIdx.x * NPB2 + local;
    if (n >= N) n = N - 1;  // duplicate work, barrier-safe

    ql[local][t] = qf[(size_t)n * HIDDEN + t];
    if (t < KNBR) {
        int iv = nbr_idx[(size_t)n * KNBR + t];
        idxl[local][t] = min(max(iv, 0), N - 1);
        mskl[local][t] = nbr_mask[(size_t)n * KNBR + t];
    }
    __syncthreads();

    #pragma unroll
    for (int kk = 0; kk < KNBR; ++kk) {
        size_t row = (size_t)idxl[local][kk] * 256;
        reinterpret_cast<unsigned int*>(&kvl[local][kk][0])[t] =
            reinterpret_cast<const unsigned int*>(kv + row)[t];
    }
    __syncthreads();

    const int kk = t >> 3, hh = t & 7;
    float s = 0.f;
    {
        const __hip_bfloat162* kp =
            reinterpret_cast<const __hip_bfloat162*>(&kvl[local][kk][hh * HDIM]);
        const float* qp = &ql[local][hh * HDIM];
        #pragma unroll
        for (int d2 = 0; d2 < HDIM / 2; ++d2) {
            float2 kf = __bfloat1622float2(kp[d2]);
            s += qp[2 * d2] * kf.x + qp[2 * d2 + 1] * kf.y;
        }
    }
    if (!mskl[local][kk]) s = -1e9f;
    sl[local][kk][hh] = s;
    __syncthreads();

    float mx = -3.0e38f;
    #pragma unroll
    for (int j = 0; j < KNBR; ++j) mx = fmaxf(mx, sl[local][j][hh]);
    float e = __expf(s - mx);
    el[local][kk][hh] = e;
    __syncthreads();
    float denom = 0.f;
    #pragma unroll
    for (int j = 0; j < KNBR; ++j) denom += el[local][j][hh];
    sl[local][kk][hh] = e / denom;
    __syncthreads();

    const int h2 = t >> 4, dd = t & 15;
    float o = 0.f;
    #pragma unroll
    for (int j = 0; j < KNBR; ++j) {
        float a = sl[local][j][h2];
        float vv = __bfloat162float(kvl[local][j][HIDDEN + h2 * HDIM + dd]);
        o += a * vv;
    }
    out[(size_t)n * HIDDEN + t] = o;  // OUTPUT IS FLOAT32 (verified r6)
}

extern "C" void kernel_launch(void* const* d_in, const int* in_sizes, int n_in,
                              void* d_out, int out_size, void* d_ws, size_t ws_size,
                              hipStream_t stream)
{
    float* out = (float*)d_out;

    bool ok = (n_in == 10);
    int N = ok ? in_sizes[0] / NFEAT : 0;
    ok = ok && N > 0 && in_sizes[0] == N * NFEAT
            && in_sizes[1] == N * KNBR
            && in_sizes[2] == N * KNBR
            && in_sizes[3] == NFEAT * VOCAB * HIDDEN
            && in_sizes[4] == HIDDEN * HIDDEN && in_sizes[5] == HIDDEN
            && in_sizes[6] == HIDDEN * HIDDEN && in_sizes[7] == HIDDEN
            && in_sizes[8] == HIDDEN * HIDDEN && in_sizes[9] == HIDDEN
            && out_size == N * HIDDEN;
    if (!ok) {
        fill_kernel<<<(out_size + 255) / 256, 256, 0, stream>>>(out, out_size, 0.0f);
        return;
    }
    size_t need = (size_t)N * 1024 + 3 * HIDDEN * HIDDEN * sizeof(short);
    if (ws_size < need) {
        fill_kernel<<<(out_size + 255) / 256, 256, 0, stream>>>(out, out_size, 1.0f);
        return;
    }

    const int* X        = (const int*)d_in[0];
    const int* nbr_idx  = (const int*)d_in[1];
    const int* nbr_mask = (const int*)d_in[2];
    const float* emb = (const float*)d_in[3];
    const float* Wq  = (const float*)d_in[4];
    const float* bq  = (const float*)d_in[5];
    const float* Wk  = (const float*)d_in[6];
    const float* bk  = (const float*)d_in[7];
    const float* Wv  = (const float*)d_in[8];
    const float* bv  = (const float*)d_in[9];

    // workspace: qf fp32 [N][128] | kv bf16 [N][256] | Wt bf16 [3][128][128]
    float* qf = (float*)d_ws;
    __hip_bfloat16* kv =
        (__hip_bfloat16*)((char*)d_ws + (size_t)N * HIDDEN * sizeof(float));
    short* Wt = (short*)((char*)d_ws + (size_t)N * 1024);

    wt_kernel<<<12, 256, 0, stream>>>(Wq, Wk, Wv, Wt);
    qkv_kernel<<<(N + MT - 1) / MT, 256, 0, stream>>>(
        X, emb, Wt, bq, bk, bv, qf, kv, N);
    attn_kernel<<<(N + NPB2 - 1) / NPB2, 256, 0, stream>>>(
        nbr_idx, nbr_mask, qf, kv, out, N);
}

// Round 9
// 187.443 us; speedup vs baseline: 1.6142x; 1.0538x over previous
//
#include <hip/hip_runtime.h>
#include <hip/hip_bf16.h>

#define NFEAT 9
#define VOCAB 119
#define HIDDEN 128
#define NHEAD 8
#define HDIM 16
#define KNBR 16

typedef __attribute__((ext_vector_type(8))) short short8;   // 8 bf16 = 4 VGPRs
typedef __attribute__((ext_vector_type(4))) float f32x4;    // MFMA C/D

// ---------- async global->LDS, 16B per lane (dest = wave-uniform base + lane*16) ----------
__device__ __forceinline__ void load_lds16(const void* g, void* l) {
    __builtin_amdgcn_global_load_lds((const __attribute__((address_space(1))) void*)g,
                                     (__attribute__((address_space(3))) void*)l, 16, 0, 0);
}

// ---------- sentinel fill (distinguishable failure signatures) ----------
__global__ void fill_kernel(float* out, int n, float val) {
    int i = blockIdx.x * blockDim.x + threadIdx.x;
    if (i < n) out[i] = val;
}

// ---------- Kernel 0: W -> W^T bf16 (one-time per launch, 12 blocks) ----------
__global__ __launch_bounds__(256) void wt_kernel(
    const float* __restrict__ Wq, const float* __restrict__ Wk,
    const float* __restrict__ Wv, short* __restrict__ Wt)
{
    int mat = blockIdx.x >> 2, tile = blockIdx.x & 3;  // 3 mats x 4 row-tiles
    const float* W = (mat == 0) ? Wq : (mat == 1) ? Wk : Wv;
    __shared__ float ls[32 * HIDDEN];
    int tid = threadIdx.x;
    int cc0 = tile * 32;
    #pragma unroll
    for (int j = 0; j < 16; ++j) {
        int idx = j * 256 + tid;
        ls[idx] = W[(size_t)cc0 * HIDDEN + idx];   // coalesced
    }
    __syncthreads();
    int c = tid & 127, hf = tid >> 7;  // thread: output row c, 16 cc's
    unsigned int ob[8];
    #pragma unroll
    for (int j = 0; j < 8; ++j) {
        int ccl = hf * 16 + 2 * j;
        __hip_bfloat16 b0 = __float2bfloat16(ls[ccl * HIDDEN + c]);
        __hip_bfloat16 b1 = __float2bfloat16(ls[(ccl + 1) * HIDDEN + c]);
        ob[j] = (unsigned int)*reinterpret_cast<unsigned short*>(&b0)
              | ((unsigned int)*reinterpret_cast<unsigned short*>(&b1) << 16);
    }
    unsigned int* dst = reinterpret_cast<unsigned int*>(
        Wt + (size_t)mat * HIDDEN * HIDDEN + (size_t)c * HIDDEN + cc0 + hf * 16);
    #pragma unroll
    for (int j = 0; j < 8; ++j) dst[j] = ob[j];
}

// ---------- Kernel 1: fused encoder + MFMA QKV ----------
// 64 nodes/block, 256 threads (4 waves). Encoder: thread = (channel-float4 x
// node-slot), 72 dwordx4 emb loads (vs 288 scalar in r8), bf16-packed ds_write_b64
// into A-operand LDS layout (stride 136 bf16 -> 2-way aliasing = free).
// MFMA phase unchanged from r8 (verified): mfma_f32_16x16x32_bf16, C mapping
// col=lane&15, row=quad*4+reg.
#define MT 64
#define HBS 136  // padded bf16 row stride; 272B = 8B-aligned, 4-bank shift/row

__global__ __launch_bounds__(256) void qkv_kernel(
    const int* __restrict__ X, const float* __restrict__ emb,
    const short* __restrict__ Wt,
    const float* __restrict__ bq, const float* __restrict__ bk,
    const float* __restrict__ bv,
    float* __restrict__ qf, __hip_bfloat16* __restrict__ kv, int N)
{
    __shared__ __align__(16) short hb[MT * HBS];
    __shared__ __align__(16) short Wb[HIDDEN * HBS];
    __shared__ int xs[MT * NFEAT];

    const int tid = threadIdx.x;
    const int n0 = blockIdx.x * MT;

    for (int i = tid; i < MT * NFEAT; i += 256) {
        int n = n0 + i / NFEAT;
        int v = (n < N) ? X[(size_t)n * NFEAT + (i % NFEAT)] : 0;
        xs[i] = min(max(v, 0), VOCAB - 1);  // clamp: never fault
    }
    __syncthreads();

    // ---- encoder: thread = (cg = float4 channel group, slot of 8 nodes) ----
    {
        const int cg = tid & 31;        // 32 groups x 4 channels
        const int slot = tid >> 5;      // 8 slots x 8 nodes
        #pragma unroll
        for (int i = 0; i < 8; ++i) {
            int nl = slot * 8 + i;
            float4 acc = {0.f, 0.f, 0.f, 0.f};
            #pragma unroll
            for (int f = 0; f < NFEAT; ++f) {
                const float4 e = *reinterpret_cast<const float4*>(
                    &emb[((size_t)f * VOCAB + xs[nl * NFEAT + f]) * HIDDEN + cg * 4]);
                acc.x += e.x; acc.y += e.y; acc.z += e.z; acc.w += e.w;
            }
            __hip_bfloat162 p0 = __float22bfloat162_rn(make_float2(acc.x, acc.y));
            __hip_bfloat162 p1 = __float22bfloat162_rn(make_float2(acc.z, acc.w));
            uint2 u;
            u.x = *reinterpret_cast<unsigned int*>(&p0);
            u.y = *reinterpret_cast<unsigned int*>(&p1);
            *reinterpret_cast<uint2*>(&hb[nl * HBS + cg * 4]) = u;  // 8B aligned
        }
    }

    const int wave = tid >> 6, lane = tid & 63;
    const int l15 = lane & 15, quad = lane >> 4;
    const int mloc = wave * 16 + l15;  // A-operand row (node within tile)

    for (int mat = 0; mat < 3; ++mat) {
        __syncthreads();  // hb ready / prior LDS reads done before restage
        const uint4* src = reinterpret_cast<const uint4*>(Wt + (size_t)mat * HIDDEN * HIDDEN);
        #pragma unroll
        for (int j = 0; j < 8; ++j) {
            int idx = j * 256 + tid;       // 2048 uint4 = 16384 bf16
            int r = idx >> 4, o = idx & 15;
            *reinterpret_cast<uint4*>(&Wb[r * HBS + o * 8]) = src[idx];
        }
        __syncthreads();

        short8 a[4];
        #pragma unroll
        for (int k0 = 0; k0 < 4; ++k0)  // A[m=mloc][k=k0*32+quad*8 ..+7]
            a[k0] = *reinterpret_cast<const short8*>(&hb[mloc * HBS + k0 * 32 + quad * 8]);

        const float* bias = (mat == 0) ? bq : (mat == 1) ? bk : bv;
        #pragma unroll
        for (int nt = 0; nt < 8; ++nt) {
            f32x4 acc = {0.f, 0.f, 0.f, 0.f};
            int n = nt * 16 + l15;         // output channel
            #pragma unroll
            for (int k0 = 0; k0 < 4; ++k0) {
                short8 b = *reinterpret_cast<const short8*>(&Wb[n * HBS + k0 * 32 + quad * 8]);
                acc = __builtin_amdgcn_mfma_f32_16x16x32_bf16(a[k0], b, acc, 0, 0, 0);
            }
            float bb = bias[n];
            #pragma unroll
            for (int r = 0; r < 4; ++r) {  // C row = quad*4+r = node within tile
                int node = n0 + wave * 16 + quad * 4 + r;
                if (node < N) {
                    float val = acc[r] + bb;
                    if (mat == 0)      qf[(size_t)node * HIDDEN + n] = val * 0.25f;
                    else if (mat == 1) kv[(size_t)node * 256 + n] = __float2bfloat16(val);
                    else               kv[(size_t)node * 256 + 128 + n] = __float2bfloat16(val);
                }
            }
        }
    }
}

// ---------------- Kernel 2: ELL sparse attention ----------------
// 2 nodes/block (128 threads each). Gather via global_load_lds width-16:
// kv rows UNPADDED (512B) so dest = wave-uniform base + lane*16 holds; whole
// 16-row gather = 4 instructions per wave (vs 16 loads + 16 LDS writes).
// Unpadded rows also make the PV read pattern exactly conflict-free.
// Softmax structure unchanged (audited r6-r8).
#define NPB2 2

__global__ __launch_bounds__(256) void attn_kernel(
    const int* __restrict__ nbr_idx, const int* __restrict__ nbr_mask,
    const float* __restrict__ qf, const __hip_bfloat16* __restrict__ kv,
    float* __restrict__ out, int N)
{
    __shared__ __align__(16) __hip_bfloat16 kvl[NPB2][KNBR][256];
    __shared__ float ql[NPB2][HIDDEN];
    __shared__ float sl[NPB2][KNBR][NHEAD + 1];
    __shared__ float el[NPB2][KNBR][NHEAD + 1];
    __shared__ int idxl[NPB2][KNBR];
    __shared__ int mskl[NPB2][KNBR];

    const int tid = threadIdx.x;
    const int local = tid >> 7; // node within block
    const int t = tid & 127;    // thread within node
    int n = blockIdx.x * NPB2 + local;
    if (n >= N) n = N - 1;  // duplicate work, barrier-safe

    ql[local][t] = qf[(size_t)n * HIDDEN + t];
    if (t < KNBR) {
        int iv = nbr_idx[(size_t)n * KNBR + t];
        idxl[local][t] = min(max(iv, 0), N - 1);
        mskl[local][t] = nbr_mask[(size_t)n * KNBR + t];
    }
    __syncthreads();

    // gather: 4 global_load_lds(16B) per wave; wave covers 8 rows (2 per issue)
    {
        const int w2 = t >> 6;       // wave within node group (uniform per wave)
        const int l = t & 63;
        #pragma unroll
        for (int j = 0; j < 4; ++j) {
            int r = 4 * j + 2 * w2 + (l >> 5);   // row this lane feeds
            const short* src = (const short*)kv
                + (size_t)idxl[local][r] * 256 + (size_t)(l & 31) * 8;
            load_lds16(src, &kvl[local][4 * j + 2 * w2][0]);  // + lane*16 implicit
        }
    }
    __syncthreads();

    // scores: thread -> (nbr kk, head hh)
    const int kk = t >> 3, hh = t & 7;
    float s = 0.f;
    {
        const __hip_bfloat162* kp =
            reinterpret_cast<const __hip_bfloat162*>(&kvl[local][kk][hh * HDIM]);
        const float* qp = &ql[local][hh * HDIM];
        #pragma unroll
        for (int d2 = 0; d2 < HDIM / 2; ++d2) {
            float2 kf = __bfloat1622float2(kp[d2]);
            s += qp[2 * d2] * kf.x + qp[2 * d2 + 1] * kf.y;
        }
    }
    if (!mskl[local][kk]) s = -1e9f;
    sl[local][kk][hh] = s;
    __syncthreads();

    float mx = -3.0e38f;
    #pragma unroll
    for (int j = 0; j < KNBR; ++j) mx = fmaxf(mx, sl[local][j][hh]);
    float e = __expf(s - mx);
    el[local][kk][hh] = e;
    __syncthreads();
    float denom = 0.f;
    #pragma unroll
    for (int j = 0; j < KNBR; ++j) denom += el[local][j][hh];
    sl[local][kk][hh] = e / denom;  // reuse sl as attn weights
    __syncthreads();

    // PV: thread -> (head h2, dim dd); bank = 8*h2 + dd/2 spans 32 banks,
    // dd-parity pairs broadcast -> conflict-free with unpadded rows.
    const int h2 = t >> 4, dd = t & 15;
    float o = 0.f;
    #pragma unroll
    for (int j = 0; j < KNBR; ++j) {
        float a = sl[local][j][h2];
        float vv = __bfloat162float(kvl[local][j][HIDDEN + h2 * HDIM + dd]);
        o += a * vv;
    }
    out[(size_t)n * HIDDEN + t] = o;  // OUTPUT IS FLOAT32 (verified r6)
}

extern "C" void kernel_launch(void* const* d_in, const int* in_sizes, int n_in,
                              void* d_out, int out_size, void* d_ws, size_t ws_size,
                              hipStream_t stream)
{
    float* out = (float*)d_out;

    bool ok = (n_in == 10);
    int N = ok ? in_sizes[0] / NFEAT : 0;
    ok = ok && N > 0 && in_sizes[0] == N * NFEAT
            && in_sizes[1] == N * KNBR
            && in_sizes[2] == N * KNBR
            && in_sizes[3] == NFEAT * VOCAB * HIDDEN
            && in_sizes[4] == HIDDEN * HIDDEN && in_sizes[5] == HIDDEN
            && in_sizes[6] == HIDDEN * HIDDEN && in_sizes[7] == HIDDEN
            && in_sizes[8] == HIDDEN * HIDDEN && in_sizes[9] == HIDDEN
            && out_size == N * HIDDEN;
    if (!ok) {
        fill_kernel<<<(out_size + 255) / 256, 256, 0, stream>>>(out, out_size, 0.0f);
        return;
    }
    size_t need = (size_t)N * 1024 + 3 * HIDDEN * HIDDEN * sizeof(short);
    if (ws_size < need) {
        fill_kernel<<<(out_size + 255) / 256, 256, 0, stream>>>(out, out_size, 1.0f);
        return;
    }

    const int* X        = (const int*)d_in[0];
    const int* nbr_idx  = (const int*)d_in[1];
    const int* nbr_mask = (const int*)d_in[2];
    const float* emb = (const float*)d_in[3];
    const float* Wq  = (const float*)d_in[4];
    const float* bq  = (const float*)d_in[5];
    const float* Wk  = (const float*)d_in[6];
    const float* bk  = (const float*)d_in[7];
    const float* Wv  = (const float*)d_in[8];
    const float* bv  = (const float*)d_in[9];

    // workspace: qf fp32 [N][128] | kv bf16 [N][256] | Wt bf16 [3][128][128]
    float* qf = (float*)d_ws;
    __hip_bfloat16* kv =
        (__hip_bfloat16*)((char*)d_ws + (size_t)N * HIDDEN * sizeof(float));
    short* Wt = (short*)((char*)d_ws + (size_t)N * 1024);

    wt_kernel<<<12, 256, 0, stream>>>(Wq, Wk, Wv, Wt);
    qkv_kernel<<<(N + MT - 1) / MT, 256, 0, stream>>>(
        X, emb, Wt, bq, bk, bv, qf, kv, N);
    attn_kernel<<<(N + NPB2 - 1) / NPB2, 256, 0, stream>>>(
        nbr_idx, nbr_mask, qf, kv, out, N);
}